// Round 3
// baseline (24333.310 us; speedup 1.0000x reference)
//
#include <hip/hip_runtime.h>

// GRU-D forward, MI355X. Sizes fixed per reference:
#define TT 200
#define KK 512
#define BB 1024
#define DD 128
#define HH 2048

typedef short short8 __attribute__((ext_vector_type(8)));
typedef float f32x4 __attribute__((ext_vector_type(4)));
typedef __bf16 bf16x8 __attribute__((ext_vector_type(8)));

#define TWO_LOGC 1.8378770664093453f  // 2*log(sqrt(2*pi))

__device__ __forceinline__ unsigned short f2bf(float f) {
  union { float f; unsigned u; } x; x.f = f;
  unsigned r = x.u + 0x7fffu + ((x.u >> 16) & 1u);
  return (unsigned short)(r >> 16);
}
__device__ __forceinline__ float bf2f(unsigned short b) {
  union { unsigned u; float f; } x; x.u = ((unsigned)b) << 16;
  return x.f;
}
__device__ __forceinline__ f32x4 mfma16(short8 a, short8 b, f32x4 c) {
  return __builtin_amdgcn_mfma_f32_16x16x32_bf16(
      __builtin_bit_cast(bf16x8, a), __builtin_bit_cast(bf16x8, b), c, 0, 0, 0);
}

typedef void __attribute__((address_space(1))) as1_void;
typedef void __attribute__((address_space(3))) as3_void;
// async global->LDS, 16B per lane; LDS dest = (uniform l) + lane*16
__device__ __forceinline__ void gld_lds16(const unsigned short* g, unsigned short* l) {
  __builtin_amdgcn_global_load_lds((as1_void*)const_cast<unsigned short*>(g),
                                   (as3_void*)l, 16, 0, 0);
}

// ---------------- tiled bf16 GEMM with fused epilogues -----------------------
// C[M,N] = A[M,Kr] * BT[N,Kr]^T ; A split at column `split` into A1|A2.
// Tile BM=32*MI x BN=32*NI, block 256 (4 waves as 2x2), wave = 16*MI x 16*NI.
// Staging: global_load_lds dwordx4, LDS linear, source chunk XOR-preswizzled.
struct GP {
  const unsigned short* A1; int lda1;
  const unsigned short* A2; int lda2; int split;
  const unsigned short* BT; int ldb;
  int Kr;
  const float* bias;
  const float* bias2;
  unsigned short* obf;
  unsigned short* obf2;
  float* of1;
  const float* f1;
  const float* f2;
  const float* f3;
  const unsigned short* u1;
  const int* idx;
  float* h;
  float* d_loss;
};

template <int MI, int NI, int EPI>
__global__ __launch_bounds__(256, (MI >= 4 ? 2 : 3)) void gemmT(GP p) {
  constexpr int BM = 32 * MI, BN = 32 * NI;
  constexpr int APW = BM / 64;  // A stage-issues per wave (16 rows each)
  constexpr int BPW = BN / 64;
  __shared__ unsigned short As[2][BM * 32];
  __shared__ unsigned short Bs[2][BN * 32];
  const int tid = threadIdx.x;
  const int lane = tid & 63;
  const int w = tid >> 6;
  const int wr = w >> 1, wc = w & 1;
  const long m0 = (long)blockIdx.x * BM;
  const int n0 = blockIdx.y * BN;

  // per-lane staging sources (row fixed per lane; chunk XOR-preswizzled so
  // the linear LDS write yields LDS(row,c) = G(row, c ^ ((row>>1)&3)))
  const int lrow = lane >> 2, lchunk = lane & 3;
  const unsigned short* ap1[APW];
  const unsigned short* ap2[APW];
  int akoff[APW];
#pragma unroll
  for (int a = 0; a < APW; ++a) {
    int row = (w * APW + a) * 16 + lrow;
    int cs = lchunk ^ ((row >> 1) & 3);
    akoff[a] = cs * 8;
    ap1[a] = p.A1 + (m0 + row) * (long)p.lda1 + cs * 8;
    ap2[a] = p.A2 + (m0 + row) * (long)p.lda2 + cs * 8 - p.split;
  }
  const unsigned short* bp[BPW];
#pragma unroll
  for (int b = 0; b < BPW; ++b) {
    int row = (w * BPW + b) * 16 + lrow;
    int cs = lchunk ^ ((row >> 1) & 3);
    bp[b] = p.BT + (long)(n0 + row) * p.ldb + cs * 8;
  }

  auto stage = [&](int cur, int k0) {
#pragma unroll
    for (int a = 0; a < APW; ++a) {
      const unsigned short* g = (k0 + akoff[a] < p.split) ? ap1[a] + k0 : ap2[a] + k0;
      gld_lds16(g, &As[cur][(w * APW + a) * 512]);
    }
#pragma unroll
    for (int b = 0; b < BPW; ++b)
      gld_lds16(bp[b] + k0, &Bs[cur][(w * BPW + b) * 512]);
  };

  const int frow = lane & 15;
  const int fg = lane >> 4;

  f32x4 acc[MI][NI] = {};

  stage(0, 0);
  int cur = 0;
  for (int k0 = 0; k0 < p.Kr; k0 += 32) {
    __syncthreads();  // vmcnt drained: tile `cur` landed; prev reads complete
    if (k0 + 32 < p.Kr) stage(cur ^ 1, k0 + 32);
    short8 af[MI], bfr[NI];
#pragma unroll
    for (int mi = 0; mi < MI; ++mi) {
      int r = wr * (16 * MI) + mi * 16 + frow;
      af[mi] = *(const short8*)&As[cur][r * 32 + ((fg ^ ((r >> 1) & 3)) << 3)];
    }
#pragma unroll
    for (int ni = 0; ni < NI; ++ni) {
      int r = wc * (16 * NI) + ni * 16 + frow;
      bfr[ni] = *(const short8*)&Bs[cur][r * 32 + ((fg ^ ((r >> 1) & 3)) << 3)];
    }
#pragma unroll
    for (int mi = 0; mi < MI; ++mi)
#pragma unroll
      for (int ni = 0; ni < NI; ++ni) acc[mi][ni] = mfma16(af[mi], bfr[ni], acc[mi][ni]);
    cur ^= 1;
  }

  // epilogue: D element (row=(lane>>4)*4+r, col=lane&15) per 16x16 frag (m89)
  float lsum = 0.f;
#pragma unroll
  for (int mi = 0; mi < MI; ++mi) {
#pragma unroll
    for (int r = 0; r < 4; ++r) {
      const long grow = m0 + wr * (16 * MI) + mi * 16 + ((lane >> 4) << 2) + r;
      int bi = 0;
      if constexpr (EPI == 2 || EPI == 4) bi = p.idx[grow];
#pragma unroll
      for (int ni = 0; ni < NI; ++ni) {
        const int gcol = n0 + wc * (16 * NI) + ni * 16 + (lane & 15);
        float v = acc[mi][ni][r];
        if constexpr (EPI == 0) {  // relu(v+bias) -> bf16 [ld HH]
          v += p.bias[gcol];
          v = fmaxf(v, 0.f);
          p.obf[grow * HH + gcol] = f2bf(v);
        } else if constexpr (EPI == 1) {  // loss; cols interleaved mean/logvar
          float bsel = (gcol & 1) ? p.bias[128 + (gcol >> 1)] : p.bias[gcol >> 1];
          float vb = v + bsel;
          float pv = __shfl_xor(vb, 1);
          if (!(gcol & 1)) {
            int d = gcol >> 1;
            long o = grow * DD + d;
            float Xo = p.f1[o], Mo = p.f2[o];
            float e = Xo - vb;
            lsum += 0.5f * Mo * (e * e * expf(-pv) + pv + TWO_LOGC);
          }
        } else if constexpr (EPI == 2) {  // gh -> hg gather, hd outputs
          float gh = expf(-fmaxf(v, 0.f));
          float hg = p.h[(long)bi * HH + gcol];
          float hd = gh * hg;
          long o = grow * HH + gcol;
          p.obf[o] = f2bf(hg);
          p.obf2[o] = f2bf(hd);
          p.of1[o] = hd;
        } else if constexpr (EPI == 3) {  // r (cols<HH) / z gates
          if (gcol < HH) {
            float rv = 1.f / (1.f + expf(-(v + p.bias[gcol])));
            long o = grow * HH + gcol;
            p.obf[o] = f2bf(rv * p.f1[o]);
          } else {
            int c = gcol - HH;
            float zv = 1.f / (1.f + expf(-(v + p.bias2[c])));
            p.of1[grow * HH + c] = zv;
          }
        } else if constexpr (EPI == 4) {  // ht -> hn -> scatter h
          float ht = tanhf(v + p.bias[gcol]);
          long o = grow * HH + gcol;
          float z = p.f1[o], hd = p.f2[o];
          p.h[(long)bi * HH + gcol] = (1.f - z) * hd + z * ht;
        } else {  // EPI 5: gx -> X_hat (all t), in-place lx->X_hat in XM
          int tt = (int)(grow >> 9);
          float gx = expf(-fmaxf(v, 0.f));
          long o = grow * DD + gcol;
          float Xo = p.f1[o], Mo = p.f2[o];
          float lx = bf2f(p.u1[grow * 256 + gcol]);
          float mx = p.f3[(long)tt * DD + gcol];
          float xh = Mo * Xo + (1.f - Mo) * (gx * lx + (1.f - gx) * mx);
          p.obf[grow * 256 + gcol] = f2bf(xh);
        }
      }
    }
  }
  if constexpr (EPI == 1) {
    for (int off = 32; off; off >>= 1) lsum += __shfl_down(lsum, off);
    if (lane == 0) atomicAdd(p.d_loss, lsum);
  }
}

// ------------- preprocessing kernels ----------------------------------------
__global__ void transpose_cvt(const float* __restrict__ src, long src_ld,
                              unsigned short* __restrict__ dst, long dst_ld,
                              long row_off, int row_stride, long col_off) {
  __shared__ float tile[32][33];
  int k0 = blockIdx.x * 32, n0 = blockIdx.y * 32;
  int tx = threadIdx.x & 31, ty = threadIdx.x >> 5;
  for (int i = ty; i < 32; i += 8) tile[i][tx] = src[(long)(k0 + i) * src_ld + n0 + tx];
  __syncthreads();
  for (int i = ty; i < 32; i += 8) {
    long n = n0 + i, k = k0 + tx;
    dst[(row_off + n * row_stride) * dst_ld + col_off + k] = f2bf(tile[tx][i]);
  }
}

__global__ void init_k(float* h, float* scal) {
  long i = (long)blockIdx.x * blockDim.x + threadIdx.x;
  if (i < (long)BB * HH) h[i] = 0.f;
  if (i < 2) scal[i] = 0.f;
}
__global__ void pos_init(int* pos) {
  int i = blockIdx.x * 256 + threadIdx.x;
  if (i < TT * BB) pos[i] = -1;
}
__global__ void pos_fill(const int* __restrict__ bidx, int* __restrict__ pos) {
  int i = blockIdx.x * 256 + threadIdx.x;
  if (i < TT * KK) {
    int t = i >> 9, k = i & 511;
    pos[t * BB + bidx[i]] = k;
  }
}
__global__ void traj(const float* __restrict__ X, const float* __restrict__ M,
                     const float* __restrict__ times, const int* __restrict__ pos,
                     unsigned short* __restrict__ iv_bf, unsigned short* __restrict__ XM) {
  int b = blockIdx.x, d = threadIdx.x;
  float lastx = 0.f, lastt = 0.f;
  for (int t = 0; t < TT; ++t) {
    int k = pos[t * BB + b];
    if (k >= 0) {
      long row = (long)t * KK + k;
      long o = row * DD + d;
      float Xo = X[o], Mo = M[o];
      float tv = times[t];
      iv_bf[o] = f2bf(tv - lastt);
      float lx = lastx * (1.f - Mo) + Xo * Mo;
      XM[row * 256 + d] = f2bf(lx);
      lastx = lx;
      lastt = lastt * (1.f - Mo) + tv * Mo;
    }
  }
}
__global__ void meanx_k(const float* __restrict__ X, const float* __restrict__ M,
                        float* __restrict__ mx) {
  int t = blockIdx.x, d = threadIdx.x;
  const float* Xb = X + (long)t * KK * DD;
  const float* Mb = M + (long)t * KK * DD;
  float sx = 0.f, sm = 0.f;
  for (int k = 0; k < KK; ++k) {
    sx += Xb[k * DD + d];
    sm += Mb[k * DD + d];
  }
  mx[t * DD + d] = sx / (sm + KK * 1e-6f);
}
__global__ void totm_k(const float* __restrict__ M, float* __restrict__ scal) {
  long n = (long)TT * KK * DD;
  float v = 0.f;
  for (long i = (long)blockIdx.x * blockDim.x + threadIdx.x; i < n;
       i += (long)gridDim.x * blockDim.x)
    v += M[i];
  for (int off = 32; off; off >>= 1) v += __shfl_down(v, off);
  if ((threadIdx.x & 63) == 0) atomicAdd(&scal[1], v);
}
__global__ void mo_fill(const float* __restrict__ M, unsigned short* __restrict__ XM) {
  long i = (long)blockIdx.x * blockDim.x + threadIdx.x;
  long n = (long)TT * KK * DD;
  if (i < n) {
    long row = i >> 7;
    int d = i & 127;
    XM[row * 256 + 128 + d] = f2bf(M[i]);
  }
}
__global__ void finish_k(const float* scal, float* out) { out[0] = scal[0] / scal[1]; }

// ---------------- host orchestration ----------------------------------------
extern "C" void kernel_launch(void* const* d_in, const int* in_sizes, int n_in,
                              void* d_out, int out_size, void* d_ws, size_t ws_size,
                              hipStream_t stream) {
  const float* times = (const float*)d_in[0];
  const float* X = (const float*)d_in[1];
  const float* M = (const float*)d_in[2];
  const float* Wp1 = (const float*)d_in[3];
  const float* bp1 = (const float*)d_in[4];
  const float* Wp2 = (const float*)d_in[5];
  const float* bp2 = (const float*)d_in[6];
  const float* W_r = (const float*)d_in[7];
  const float* V_r = (const float*)d_in[8];
  const float* U_r = (const float*)d_in[9];
  const float* W_z = (const float*)d_in[10];
  const float* V_z = (const float*)d_in[11];
  const float* U_z = (const float*)d_in[12];
  const float* W_h = (const float*)d_in[13];
  const float* V_h = (const float*)d_in[14];
  const float* U_h = (const float*)d_in[15];
  const float* b_r = (const float*)d_in[16];
  const float* b_z = (const float*)d_in[17];
  const float* b_h = (const float*)d_in[18];
  const float* Wgx = (const float*)d_in[19];
  const float* Wgh = (const float*)d_in[20];
  const int* bidx = (const int*)d_in[21];

  char* wp = (char*)d_ws;
  auto alloc = [&](size_t n) {
    char* r = wp;
    wp += (n + 1023) & ~(size_t)1023;
    return r;
  };
  float* h = (float*)alloc((size_t)BB * HH * 4);
  unsigned short* P1T = (unsigned short*)alloc((size_t)HH * HH * 2);
  unsigned short* P2T = (unsigned short*)alloc((size_t)256 * HH * 2);
  unsigned short* GxT = (unsigned short*)alloc((size_t)DD * DD * 2);
  unsigned short* GhT = (unsigned short*)alloc((size_t)HH * DD * 2);
  unsigned short* B4T = (unsigned short*)alloc((size_t)2 * HH * 2304 * 2);
  unsigned short* B5T = (unsigned short*)alloc((size_t)HH * 2304 * 2);
  unsigned short* iv_bf = (unsigned short*)alloc((size_t)TT * KK * DD * 2);
  unsigned short* XM = (unsigned short*)alloc((size_t)TT * KK * 256 * 2);
  float* meanx = (float*)alloc((size_t)TT * DD * 4);
  int* pos = (int*)alloc((size_t)TT * BB * 4);
  unsigned short* hd_bf = (unsigned short*)alloc((size_t)KK * HH * 2);
  float* hd_f32 = (float*)alloc((size_t)KK * HH * 4);
  unsigned short* rh_bf = (unsigned short*)alloc((size_t)KK * HH * 2);
  float* zbuf = (float*)alloc((size_t)KK * HH * 4);
  float* scal = (float*)alloc(1024);

  // loss-batch ring buffers, sized from remaining workspace (4 MiB per step)
  size_t used = (size_t)(wp - (char*)d_ws);
  size_t slot = (size_t)KK * HH * 2;  // 2 MiB
  long rem = (long)ws_size - (long)used;
  int NB = (int)(rem / (long)(2 * slot));
  if (NB < 1) NB = 1;
  if (NB > 50) NB = 50;
  unsigned short* hgr = (unsigned short*)alloc(slot * NB);
  unsigned short* A1r = (unsigned short*)alloc(slot * NB);

  dim3 blk(256);

  init_k<<<(BB * HH + 255) / 256, blk, 0, stream>>>(h, scal);
  pos_init<<<(TT * BB + 255) / 256, blk, 0, stream>>>(pos);
  pos_fill<<<(TT * KK + 255) / 256, blk, 0, stream>>>(bidx, pos);

  auto tc = [&](const float* src, long src_ld, unsigned short* dst, long dst_ld, int KR,
                int NC, long row_off, int row_stride, long col_off) {
    transpose_cvt<<<dim3(KR / 32, NC / 32), blk, 0, stream>>>(src, src_ld, dst, dst_ld,
                                                              row_off, row_stride, col_off);
  };
  tc(Wp1, HH, P1T, HH, HH, HH, 0, 1, 0);
  tc(Wp2, 256, P2T, HH, HH, 128, 0, 2, 0);        // mean cols -> even rows
  tc(Wp2 + 128, 256, P2T, HH, HH, 128, 1, 2, 0);  // logvar cols -> odd rows
  tc(Wgx, DD, GxT, DD, DD, DD, 0, 1, 0);
  tc(Wgh, HH, GhT, DD, DD, HH, 0, 1, 0);
  // B4T rows: [U_r;W_r;V_r] cols 0..2047, [U_z;W_z;V_z] cols 2048..4095 (ld 2304)
  tc(U_r, HH, B4T, 2304, HH, HH, 0, 1, 0);
  tc(W_r, HH, B4T, 2304, DD, HH, 0, 1, 2048);
  tc(V_r, HH, B4T, 2304, DD, HH, 0, 1, 2176);
  tc(U_z, HH, B4T, 2304, HH, HH, 2048, 1, 0);
  tc(W_z, HH, B4T, 2304, DD, HH, 2048, 1, 2048);
  tc(V_z, HH, B4T, 2304, DD, HH, 2048, 1, 2176);
  tc(U_h, HH, B5T, 2304, HH, HH, 0, 1, 0);
  tc(W_h, HH, B5T, 2304, DD, HH, 0, 1, 2048);
  tc(V_h, HH, B5T, 2304, DD, HH, 0, 1, 2176);

  meanx_k<<<TT, dim3(DD), 0, stream>>>(X, M, meanx);
  traj<<<BB, dim3(DD), 0, stream>>>(X, M, times, pos, iv_bf, XM);
  totm_k<<<1024, blk, 0, stream>>>(M, scal);
  mo_fill<<<(TT * KK * DD + 255) / 256, blk, 0, stream>>>(M, XM);

  // gx GEMM over all t + X_hat epilogue (in-place into XM cols 0..127)
  {
    GP g = {};
    g.A1 = iv_bf; g.lda1 = DD; g.A2 = iv_bf; g.lda2 = DD; g.split = 1 << 30;
    g.BT = GxT; g.ldb = DD; g.Kr = DD;
    g.f1 = X; g.f2 = M; g.f3 = meanx; g.u1 = XM; g.obf = XM;
    gemmT<2, 4, 5><<<dim3(TT * KK / 64, DD / 128), blk, 0, stream>>>(g);
  }

  int t0 = 0;
  for (int t = 0; t < TT; ++t) {
    const int* idx_t = bidx + t * KK;
    const unsigned short* XMt = XM + (size_t)t * KK * 256;
    unsigned short* hg_t = hgr + (size_t)(t - t0) * KK * HH;
    // S1: gh = exp(-relu(iv@Wgh)); gather hg; hd = gh*hg
    {
      GP g = {};
      g.A1 = iv_bf + (size_t)t * KK * DD; g.lda1 = DD;
      g.A2 = g.A1; g.lda2 = DD; g.split = 1 << 30;
      g.BT = GhT; g.ldb = DD; g.Kr = DD;
      g.obf = hg_t; g.obf2 = hd_bf; g.of1 = hd_f32; g.idx = idx_t; g.h = h;
      gemmT<2, 4, 2><<<dim3(KK / 64, HH / 128), blk, 0, stream>>>(g);
    }
    // S4: r,z = sigmoid([hd|X_hat|Mo] @ B4T + b)
    {
      GP g = {};
      g.A1 = hd_bf; g.lda1 = HH; g.A2 = XMt; g.lda2 = 256; g.split = HH;
      g.BT = B4T; g.ldb = 2304; g.Kr = 2304;
      g.bias = b_r; g.bias2 = b_z; g.obf = rh_bf; g.f1 = hd_f32; g.of1 = zbuf;
      gemmT<2, 4, 3><<<dim3(KK / 64, 2 * HH / 128), blk, 0, stream>>>(g);
    }
    // S5: ht = tanh([r*hd|X_hat|Mo] @ B5T + b_h); hn -> scatter h
    {
      GP g = {};
      g.A1 = rh_bf; g.lda1 = HH; g.A2 = XMt; g.lda2 = 256; g.split = HH;
      g.BT = B5T; g.ldb = 2304; g.Kr = 2304;
      g.bias = b_h; g.f1 = zbuf; g.f2 = hd_f32; g.idx = idx_t; g.h = h;
      gemmT<2, 4, 4><<<dim3(KK / 64, HH / 128), blk, 0, stream>>>(g);
    }
    // batched loss path (off the recurrence critical state): S2b then S3b
    if (t - t0 + 1 == NB || t == TT - 1) {
      int cnt = t - t0 + 1;
      {
        GP g = {};
        g.A1 = hgr; g.lda1 = HH; g.A2 = hgr; g.lda2 = HH; g.split = 1 << 30;
        g.BT = P1T; g.ldb = HH; g.Kr = HH;
        g.bias = bp1; g.obf = A1r;
        gemmT<4, 4, 0><<<dim3(cnt * KK / 128, HH / 128), blk, 0, stream>>>(g);
      }
      {
        GP g = {};
        g.A1 = A1r; g.lda1 = HH; g.A2 = A1r; g.lda2 = HH; g.split = 1 << 30;
        g.BT = P2T; g.ldb = HH; g.Kr = HH;
        g.bias = bp2; g.f1 = X + (size_t)t0 * KK * DD; g.f2 = M + (size_t)t0 * KK * DD;
        g.d_loss = scal;
        gemmT<4, 4, 1><<<dim3(cnt * KK / 128, 256 / 128), blk, 0, stream>>>(g);
      }
      t0 = t + 1;
    }
  }
  finish_k<<<1, 1, 0, stream>>>(scal, (float*)d_out);
}

// Round 4
// 14029.016 us; speedup vs baseline: 1.7345x; 1.7345x over previous
//
#include <hip/hip_runtime.h>

// GRU-D forward, MI355X. Sizes fixed per reference:
#define TT 200
#define KK 512
#define BB 1024
#define DD 128
#define HH 2048

typedef short short8 __attribute__((ext_vector_type(8)));
typedef float f32x4 __attribute__((ext_vector_type(4)));
typedef __bf16 bf16x8 __attribute__((ext_vector_type(8)));

#define TWO_LOGC 1.8378770664093453f  // 2*log(sqrt(2*pi))

__device__ __forceinline__ unsigned short f2bf(float f) {
  union { float f; unsigned u; } x; x.f = f;
  unsigned r = x.u + 0x7fffu + ((x.u >> 16) & 1u);
  return (unsigned short)(r >> 16);
}
__device__ __forceinline__ float bf2f(unsigned short b) {
  union { unsigned u; float f; } x; x.u = ((unsigned)b) << 16;
  return x.f;
}
__device__ __forceinline__ f32x4 mfma16(short8 a, short8 b, f32x4 c) {
  return __builtin_amdgcn_mfma_f32_16x16x32_bf16(
      __builtin_bit_cast(bf16x8, a), __builtin_bit_cast(bf16x8, b), c, 0, 0, 0);
}

typedef void __attribute__((address_space(1))) as1_void;
typedef void __attribute__((address_space(3))) as3_void;
// async global->LDS, 16B per lane; LDS dest = (uniform base) + lane*16
__device__ __forceinline__ void gld_lds16(const unsigned short* g, unsigned short* l) {
  __builtin_amdgcn_global_load_lds((as1_void*)const_cast<unsigned short*>(g),
                                   (as3_void*)l, 16, 0, 0);
}

// ---------------- pipelined bf16 GEMM with fused epilogues -------------------
// C[M,N] = A[M,Kr] * BT[N,Kr]^T ; A split at column `split` (multiple of 32).
// Block 256 thr = 4 waves (2x2); wave tile 16*MI x 16*NI; BM=32*MI, BN=32*NI.
// 4-deep LDS ring, counted s_waitcnt vmcnt(2L) (never 0 in-loop), raw barrier.
struct GP {
  const unsigned short* A1; int lda1;
  const unsigned short* A2; int lda2; int split;
  const unsigned short* BT; int ldb;
  int Kr;
  const float* bias;
  const float* bias2;
  unsigned short* obf;
  unsigned short* obf2;
  float* of1;
  const float* f1;
  const float* f2;
  const float* f3;
  const unsigned short* u1;
  const int* idx;
  float* h;
  float* d_loss;
};

template <int MI, int NI, int EPI>
__global__ __launch_bounds__(256, 2) void gemmP(GP p) {
  constexpr int BM = 32 * MI, BN = 32 * NI;
  constexpr int L = (MI + NI) / 2;  // stage-issues per wave per k-tile
  __shared__ unsigned short As[4][BM * 32];
  __shared__ unsigned short Bs[4][BN * 32];
  const int tid = threadIdx.x;
  const int lane = tid & 63;
  const int w = tid >> 6;
  const int wr = w >> 1, wc = w & 1;
  const long m0 = (long)blockIdx.x * BM;
  const int n0 = blockIdx.y * BN;

  // staging chunk descriptors: chunk c = w*L + j; c<2*MI -> A rows [c*16,..),
  // else B rows. lane -> (row = base+lane>>2, k-chunk cs pre-XOR-swizzled so
  // linear LDS write gives LDS(r,c) = G(r, c ^ ((r>>1)&3)).
  const int lrow = lane >> 2;
  const unsigned short* gA1[L];
  const unsigned short* gA2[L];
  const unsigned short* gB[L];
  unsigned short* lds0[L];
  int sstr[L];
  bool isA[L];
#pragma unroll
  for (int j = 0; j < L; ++j) {
    int c = w * L + j;
    if (c < 2 * MI) {
      int r = c * 16 + lrow;
      int cs = (lane & 3) ^ ((r >> 1) & 3);
      isA[j] = true;
      gA1[j] = p.A1 + (m0 + r) * (long)p.lda1 + cs * 8;
      gA2[j] = p.A2 + (m0 + r) * (long)p.lda2 + cs * 8 - p.split;
      gB[j] = gA1[j];
      lds0[j] = &As[0][c * 512];
      sstr[j] = BM * 32;
    } else {
      int cb = c - 2 * MI;
      int r = cb * 16 + lrow;
      int cs = (lane & 3) ^ ((r >> 1) & 3);
      isA[j] = false;
      gB[j] = p.BT + (long)(n0 + r) * p.ldb + cs * 8;
      gA1[j] = gB[j]; gA2[j] = gB[j];
      lds0[j] = &Bs[0][cb * 512];
      sstr[j] = BN * 32;
    }
  }

  auto stage = [&](int slot, int k0) {
#pragma unroll
    for (int j = 0; j < L; ++j) {
      const unsigned short* g =
          isA[j] ? ((k0 < p.split) ? gA1[j] + k0 : gA2[j] + k0) : gB[j] + k0;
      gld_lds16(g, lds0[j] + slot * sstr[j]);
    }
  };

  const int frow = lane & 15;
  const int fg = lane >> 4;

  f32x4 acc[MI][NI] = {};

  const int nIter = p.Kr >> 5;  // all users have nIter >= 4
  stage(0, 0);
  stage(1, 32);
  stage(2, 64);
  for (int i = 0; i < nIter; ++i) {
    asm volatile("s_waitcnt vmcnt(%0)" ::"i"(2 * L) : "memory");
    __builtin_amdgcn_s_barrier();
    __builtin_amdgcn_sched_barrier(0);
    const int slot = i & 3;
    short8 af[MI], bfr[NI];
#pragma unroll
    for (int mi = 0; mi < MI; ++mi) {
      int r = wr * (16 * MI) + mi * 16 + frow;
      af[mi] = *(const short8*)&As[slot][r * 32 + ((fg ^ ((r >> 1) & 3)) << 3)];
    }
#pragma unroll
    for (int ni = 0; ni < NI; ++ni) {
      int r = wc * (16 * NI) + ni * 16 + frow;
      bfr[ni] = *(const short8*)&Bs[slot][r * 32 + ((fg ^ ((r >> 1) & 3)) << 3)];
    }
#pragma unroll
    for (int mi = 0; mi < MI; ++mi)
#pragma unroll
      for (int ni = 0; ni < NI; ++ni) acc[mi][ni] = mfma16(af[mi], bfr[ni], acc[mi][ni]);
    int j3 = i + 3;
    if (j3 >= nIter) j3 = nIter - 1;  // clamped dummy keeps in-flight = 3L
    stage((i + 3) & 3, j3 * 32);
  }

  // epilogue: D element (row=(lane>>4)*4+r, col=lane&15) per 16x16 frag (m89)
  float lsum = 0.f;
#pragma unroll
  for (int mi = 0; mi < MI; ++mi) {
#pragma unroll
    for (int r = 0; r < 4; ++r) {
      const long grow = m0 + wr * (16 * MI) + mi * 16 + ((lane >> 4) << 2) + r;
      int bi = 0;
      if constexpr (EPI == 2 || EPI == 4) bi = p.idx[grow];
#pragma unroll
      for (int ni = 0; ni < NI; ++ni) {
        const int gcol = n0 + wc * (16 * NI) + ni * 16 + (lane & 15);
        float v = acc[mi][ni][r];
        if constexpr (EPI == 0) {  // relu(v+bias) -> bf16 [ld HH]
          v += p.bias[gcol];
          v = fmaxf(v, 0.f);
          p.obf[grow * HH + gcol] = f2bf(v);
        } else if constexpr (EPI == 1) {  // loss; cols interleaved mean/logvar
          float bsel = (gcol & 1) ? p.bias[128 + (gcol >> 1)] : p.bias[gcol >> 1];
          float vb = v + bsel;
          float pv = __shfl_xor(vb, 1);
          if (!(gcol & 1)) {
            int d = gcol >> 1;
            long o = grow * DD + d;
            float Xo = p.f1[o], Mo = p.f2[o];
            float e = Xo - vb;
            lsum += 0.5f * Mo * (e * e * expf(-pv) + pv + TWO_LOGC);
          }
        } else if constexpr (EPI == 2) {  // gh -> hg gather, hd outputs
          float gh = expf(-fmaxf(v, 0.f));
          float hg = p.h[(long)bi * HH + gcol];
          float hd = gh * hg;
          long o = grow * HH + gcol;
          p.obf[o] = f2bf(hg);
          p.obf2[o] = f2bf(hd);
          p.of1[o] = hd;
        } else if constexpr (EPI == 3) {  // r (cols<HH) / z gates
          if (gcol < HH) {
            float rv = 1.f / (1.f + expf(-(v + p.bias[gcol])));
            long o = grow * HH + gcol;
            p.obf[o] = f2bf(rv * p.f1[o]);
          } else {
            int c = gcol - HH;
            float zv = 1.f / (1.f + expf(-(v + p.bias2[c])));
            p.of1[grow * HH + c] = zv;
          }
        } else if constexpr (EPI == 4) {  // ht -> hn -> scatter h
          float ht = tanhf(v + p.bias[gcol]);
          long o = grow * HH + gcol;
          float z = p.f1[o], hd = p.f2[o];
          p.h[(long)bi * HH + gcol] = (1.f - z) * hd + z * ht;
        } else {  // EPI 5: gx -> X_hat (all t), in-place lx->X_hat in XM
          int tt = (int)(grow >> 9);
          float gx = expf(-fmaxf(v, 0.f));
          long o = grow * DD + gcol;
          float Xo = p.f1[o], Mo = p.f2[o];
          float lx = bf2f(p.u1[grow * 256 + gcol]);
          float mx = p.f3[(long)tt * DD + gcol];
          float xh = Mo * Xo + (1.f - Mo) * (gx * lx + (1.f - gx) * mx);
          p.obf[grow * 256 + gcol] = f2bf(xh);
        }
      }
    }
  }
  if constexpr (EPI == 1) {
    for (int off = 32; off; off >>= 1) lsum += __shfl_down(lsum, off);
    if (lane == 0) atomicAdd(p.d_loss, lsum);
  }
}

// ------------- preprocessing kernels ----------------------------------------
__global__ void transpose_cvt(const float* __restrict__ src, long src_ld,
                              unsigned short* __restrict__ dst, long dst_ld,
                              long row_off, int row_stride, long col_off) {
  __shared__ float tile[32][33];
  int k0 = blockIdx.x * 32, n0 = blockIdx.y * 32;
  int tx = threadIdx.x & 31, ty = threadIdx.x >> 5;
  for (int i = ty; i < 32; i += 8) tile[i][tx] = src[(long)(k0 + i) * src_ld + n0 + tx];
  __syncthreads();
  for (int i = ty; i < 32; i += 8) {
    long n = n0 + i, k = k0 + tx;
    dst[(row_off + n * row_stride) * dst_ld + col_off + k] = f2bf(tile[tx][i]);
  }
}

__global__ void init_k(float* h, float* scal) {
  long i = (long)blockIdx.x * blockDim.x + threadIdx.x;
  if (i < (long)BB * HH) h[i] = 0.f;
  if (i < 2) scal[i] = 0.f;
}
__global__ void pos_init(int* pos) {
  int i = blockIdx.x * 256 + threadIdx.x;
  if (i < TT * BB) pos[i] = -1;
}
__global__ void pos_fill(const int* __restrict__ bidx, int* __restrict__ pos) {
  int i = blockIdx.x * 256 + threadIdx.x;
  if (i < TT * KK) {
    int t = i >> 9, k = i & 511;
    pos[t * BB + bidx[i]] = k;
  }
}
__global__ void traj(const float* __restrict__ X, const float* __restrict__ M,
                     const float* __restrict__ times, const int* __restrict__ pos,
                     unsigned short* __restrict__ iv_bf, unsigned short* __restrict__ XM) {
  int b = blockIdx.x, d = threadIdx.x;
  float lastx = 0.f, lastt = 0.f;
  for (int t = 0; t < TT; ++t) {
    int k = pos[t * BB + b];
    if (k >= 0) {
      long row = (long)t * KK + k;
      long o = row * DD + d;
      float Xo = X[o], Mo = M[o];
      float tv = times[t];
      iv_bf[o] = f2bf(tv - lastt);
      float lx = lastx * (1.f - Mo) + Xo * Mo;
      XM[row * 256 + d] = f2bf(lx);
      lastx = lx;
      lastt = lastt * (1.f - Mo) + tv * Mo;
    }
  }
}
__global__ void meanx_k(const float* __restrict__ X, const float* __restrict__ M,
                        float* __restrict__ mx) {
  int t = blockIdx.x, d = threadIdx.x;
  const float* Xb = X + (long)t * KK * DD;
  const float* Mb = M + (long)t * KK * DD;
  float sx = 0.f, sm = 0.f;
  for (int k = 0; k < KK; ++k) {
    sx += Xb[k * DD + d];
    sm += Mb[k * DD + d];
  }
  mx[t * DD + d] = sx / (sm + KK * 1e-6f);
}
__global__ void totm_k(const float* __restrict__ M, float* __restrict__ scal) {
  long n = (long)TT * KK * DD;
  float v = 0.f;
  for (long i = (long)blockIdx.x * blockDim.x + threadIdx.x; i < n;
       i += (long)gridDim.x * blockDim.x)
    v += M[i];
  for (int off = 32; off; off >>= 1) v += __shfl_down(v, off);
  if ((threadIdx.x & 63) == 0) atomicAdd(&scal[1], v);
}
__global__ void mo_fill(const float* __restrict__ M, unsigned short* __restrict__ XM) {
  long i = (long)blockIdx.x * blockDim.x + threadIdx.x;
  long n = (long)TT * KK * DD;
  if (i < n) {
    long row = i >> 7;
    int d = i & 127;
    XM[row * 256 + 128 + d] = f2bf(M[i]);
  }
}
__global__ void finish_k(const float* scal, float* out) { out[0] = scal[0] / scal[1]; }

// ---------------- host orchestration ----------------------------------------
extern "C" void kernel_launch(void* const* d_in, const int* in_sizes, int n_in,
                              void* d_out, int out_size, void* d_ws, size_t ws_size,
                              hipStream_t stream) {
  const float* times = (const float*)d_in[0];
  const float* X = (const float*)d_in[1];
  const float* M = (const float*)d_in[2];
  const float* Wp1 = (const float*)d_in[3];
  const float* bp1 = (const float*)d_in[4];
  const float* Wp2 = (const float*)d_in[5];
  const float* bp2 = (const float*)d_in[6];
  const float* W_r = (const float*)d_in[7];
  const float* V_r = (const float*)d_in[8];
  const float* U_r = (const float*)d_in[9];
  const float* W_z = (const float*)d_in[10];
  const float* V_z = (const float*)d_in[11];
  const float* U_z = (const float*)d_in[12];
  const float* W_h = (const float*)d_in[13];
  const float* V_h = (const float*)d_in[14];
  const float* U_h = (const float*)d_in[15];
  const float* b_r = (const float*)d_in[16];
  const float* b_z = (const float*)d_in[17];
  const float* b_h = (const float*)d_in[18];
  const float* Wgx = (const float*)d_in[19];
  const float* Wgh = (const float*)d_in[20];
  const int* bidx = (const int*)d_in[21];

  char* wp = (char*)d_ws;
  auto alloc = [&](size_t n) {
    char* r = wp;
    wp += (n + 1023) & ~(size_t)1023;
    return r;
  };
  float* h = (float*)alloc((size_t)BB * HH * 4);
  unsigned short* P1T = (unsigned short*)alloc((size_t)HH * HH * 2);
  unsigned short* P2T = (unsigned short*)alloc((size_t)256 * HH * 2);
  unsigned short* GxT = (unsigned short*)alloc((size_t)DD * DD * 2);
  unsigned short* GhT = (unsigned short*)alloc((size_t)HH * DD * 2);
  unsigned short* B4T = (unsigned short*)alloc((size_t)2 * HH * 2304 * 2);
  unsigned short* B5T = (unsigned short*)alloc((size_t)HH * 2304 * 2);
  unsigned short* iv_bf = (unsigned short*)alloc((size_t)TT * KK * DD * 2);
  unsigned short* XM = (unsigned short*)alloc((size_t)TT * KK * 256 * 2);
  float* meanx = (float*)alloc((size_t)TT * DD * 4);
  int* pos = (int*)alloc((size_t)TT * BB * 4);
  unsigned short* hd_bf = (unsigned short*)alloc((size_t)KK * HH * 2);
  float* hd_f32 = (float*)alloc((size_t)KK * HH * 4);
  unsigned short* rh_bf = (unsigned short*)alloc((size_t)KK * HH * 2);
  float* zbuf = (float*)alloc((size_t)KK * HH * 4);
  float* scal = (float*)alloc(1024);

  // loss-batch ring buffers, sized from remaining workspace (4 MiB per step)
  size_t used = (size_t)(wp - (char*)d_ws);
  size_t slot = (size_t)KK * HH * 2;  // 2 MiB
  long rem = (long)ws_size - (long)used;
  int NB = (int)(rem / (long)(2 * slot));
  if (NB < 1) NB = 1;
  if (NB > 50) NB = 50;
  unsigned short* hgr = (unsigned short*)alloc(slot * NB);
  unsigned short* A1r = (unsigned short*)alloc(slot * NB);

  dim3 blk(256);

  init_k<<<(BB * HH + 255) / 256, blk, 0, stream>>>(h, scal);
  pos_init<<<(TT * BB + 255) / 256, blk, 0, stream>>>(pos);
  pos_fill<<<(TT * KK + 255) / 256, blk, 0, stream>>>(bidx, pos);

  auto tc = [&](const float* src, long src_ld, unsigned short* dst, long dst_ld, int KR,
                int NC, long row_off, int row_stride, long col_off) {
    transpose_cvt<<<dim3(KR / 32, NC / 32), blk, 0, stream>>>(src, src_ld, dst, dst_ld,
                                                              row_off, row_stride, col_off);
  };
  tc(Wp1, HH, P1T, HH, HH, HH, 0, 1, 0);
  tc(Wp2, 256, P2T, HH, HH, 128, 0, 2, 0);        // mean cols -> even rows
  tc(Wp2 + 128, 256, P2T, HH, HH, 128, 1, 2, 0);  // logvar cols -> odd rows
  tc(Wgx, DD, GxT, DD, DD, DD, 0, 1, 0);
  tc(Wgh, HH, GhT, DD, DD, HH, 0, 1, 0);
  // B4T rows: [U_r;W_r;V_r] cols 0..2047, [U_z;W_z;V_z] cols 2048..4095 (ld 2304)
  tc(U_r, HH, B4T, 2304, HH, HH, 0, 1, 0);
  tc(W_r, HH, B4T, 2304, DD, HH, 0, 1, 2048);
  tc(V_r, HH, B4T, 2304, DD, HH, 0, 1, 2176);
  tc(U_z, HH, B4T, 2304, HH, HH, 2048, 1, 0);
  tc(W_z, HH, B4T, 2304, DD, HH, 2048, 1, 2048);
  tc(V_z, HH, B4T, 2304, DD, HH, 2048, 1, 2176);
  tc(U_h, HH, B5T, 2304, HH, HH, 0, 1, 0);
  tc(W_h, HH, B5T, 2304, DD, HH, 0, 1, 2048);
  tc(V_h, HH, B5T, 2304, DD, HH, 0, 1, 2176);

  meanx_k<<<TT, dim3(DD), 0, stream>>>(X, M, meanx);
  traj<<<BB, dim3(DD), 0, stream>>>(X, M, times, pos, iv_bf, XM);
  totm_k<<<1024, blk, 0, stream>>>(M, scal);
  mo_fill<<<(TT * KK * DD + 255) / 256, blk, 0, stream>>>(M, XM);

  // gx GEMM over all t + X_hat epilogue (in-place into XM cols 0..127)
  {
    GP g = {};
    g.A1 = iv_bf; g.lda1 = DD; g.A2 = iv_bf; g.lda2 = DD; g.split = 1 << 30;
    g.BT = GxT; g.ldb = DD; g.Kr = DD;
    g.f1 = X; g.f2 = M; g.f3 = meanx; g.u1 = XM; g.obf = XM;
    gemmP<2, 4, 5><<<dim3(TT * KK / 64, 1), blk, 0, stream>>>(g);
  }

  int t0 = 0;
  for (int t = 0; t < TT; ++t) {
    const int* idx_t = bidx + t * KK;
    const unsigned short* XMt = XM + (size_t)t * KK * 256;
    unsigned short* hg_t = hgr + (size_t)(t - t0) * KK * HH;
    // S1: gh = exp(-relu(iv@Wgh)); gather hg; hd = gh*hg
    {
      GP g = {};
      g.A1 = iv_bf + (size_t)t * KK * DD; g.lda1 = DD;
      g.A2 = g.A1; g.lda2 = DD; g.split = 1 << 30;
      g.BT = GhT; g.ldb = DD; g.Kr = DD;
      g.obf = hg_t; g.obf2 = hd_bf; g.of1 = hd_f32; g.idx = idx_t; g.h = h;
      gemmP<2, 2, 2><<<dim3(KK / 64, HH / 64), blk, 0, stream>>>(g);
    }
    // S4: r,z = sigmoid([hd|X_hat|Mo] @ B4T + b)  tile 128x64
    {
      GP g = {};
      g.A1 = hd_bf; g.lda1 = HH; g.A2 = XMt; g.lda2 = 256; g.split = HH;
      g.BT = B4T; g.ldb = 2304; g.Kr = 2304;
      g.bias = b_r; g.bias2 = b_z; g.obf = rh_bf; g.f1 = hd_f32; g.of1 = zbuf;
      gemmP<4, 2, 3><<<dim3(KK / 128, 2 * HH / 64), blk, 0, stream>>>(g);
    }
    // S5: ht = tanh([r*hd|X_hat|Mo] @ B5T + b_h); hn -> scatter h  tile 64x64
    {
      GP g = {};
      g.A1 = rh_bf; g.lda1 = HH; g.A2 = XMt; g.lda2 = 256; g.split = HH;
      g.BT = B5T; g.ldb = 2304; g.Kr = 2304;
      g.bias = b_h; g.f1 = zbuf; g.f2 = hd_f32; g.idx = idx_t; g.h = h;
      gemmP<2, 2, 4><<<dim3(KK / 64, HH / 64), blk, 0, stream>>>(g);
    }
    // batched loss path (off the recurrence critical state): S2b then S3b
    if (t - t0 + 1 == NB || t == TT - 1) {
      int cnt = t - t0 + 1;
      {
        GP g = {};
        g.A1 = hgr; g.lda1 = HH; g.A2 = hgr; g.lda2 = HH; g.split = 1 << 30;
        g.BT = P1T; g.ldb = HH; g.Kr = HH;
        g.bias = bp1; g.obf = A1r;
        gemmP<4, 4, 0><<<dim3(cnt * KK / 128, HH / 128), blk, 0, stream>>>(g);
      }
      {
        GP g = {};
        g.A1 = A1r; g.lda1 = HH; g.A2 = A1r; g.lda2 = HH; g.split = 1 << 30;
        g.BT = P2T; g.ldb = HH; g.Kr = HH;
        g.bias = bp2; g.f1 = X + (size_t)t0 * KK * DD; g.f2 = M + (size_t)t0 * KK * DD;
        g.d_loss = scal;
        gemmP<4, 4, 1><<<dim3(cnt * KK / 128, 256 / 128), blk, 0, stream>>>(g);
      }
      t0 = t + 1;
    }
  }
  finish_k<<<1, 1, 0, stream>>>(scal, (float*)d_out);
}